// Round 8
// baseline (253.400 us; speedup 1.0000x reference)
//
#include <hip/hip_runtime.h>
#include <hip/hip_fp16.h>

// Fused 8-step diffusion, v9: v1 geometry (1.25x halo) x v8 load order.
//
// v8 post-mortem (88.2us, prediction matched): k-outer independent loads
// fixed the latency-bound load phase (127->88). Split now: load ~53us,
// step ~35us. Load reads 226MB logical (1.5x weight halo) at ~4.3TB/s
// blended -- near service rate, so the lever is BYTES: drop halo redundancy
// 1.5x -> 1.25x via the v1 geometry (2 blocks/plane, 80-row window = 64
// owned + 8+8 halo, RPT=5), which also computes 17% fewer step rows.
// v1 ran this clean at 120 VGPR; its flaw (serialized p-outer load) is
// replaced by v8's k-outer unnormalized-pack stream. Row-4 weights go to
// LDS (same-thread slot, no barrier needed) since 5x18 regs won't fit.
//
// Carried techniques: XCD-chunked bijective swizzle (512%8==0, chunk 64:
// XCD k gets planes 32k..32k+31, both halves -> halo re-reads L2-local);
// two-barrier exchange (v3's single-barrier raced); fp16 packed weights,
// fp32 sums inline, register/LDS normalize post-pass; x loads after the
// weight loop to keep peak VGPR <= 128 (the 512-thread shape is the only
// one that escapes the 64-VGPR allocator trap, v5/v6).

constexpr int H = 128, W = 128, PLANE = H * W;
constexpr int NSTEP = 8;
constexpr int RPT  = 5;            // rows per thread (80-row window / 16 rg)
constexpr int NRG  = 16;
constexpr int HALO = 8;
constexpr int OWN  = 64;           // owned rows per block (2 blocks/plane)

// 6-wide column window (cols j0-1 .. j0+4) from a float4 row segment
#define MKWIN(D, V) do {                                                     \
    (D)[1] = (V).x; (D)[2] = (V).y; (D)[3] = (V).z; (D)[4] = (V).w;          \
    float _l = __shfl_up((V).w, 1);                                          \
    float _r = __shfl_down((V).x, 1);                                        \
    (D)[0] = (quad == 0)  ? 0.f : _l;                                        \
    (D)[5] = (quad == 31) ? 0.f : _r;                                        \
} while (0)

__global__ __launch_bounds__(512)
void diff_fused(const float* __restrict__ xin,
                const float* __restrict__ wgt,
                float* __restrict__ out)
{
    __shared__ float ldsT[NRG][W];      // each rg's top row    (8 KB)
    __shared__ float ldsB[NRG][W];      // each rg's bottom row (8 KB)
    __shared__ uint2 whL[9][512];       // p=4 weights, fp16x4/thread (36 KB)

    const int tid   = threadIdx.x;
    const int quad  = tid & 31;         // cols 4q..4q+3
    const int rg    = tid >> 5;         // 0..15
    const int j0    = quad * 4;

    // XCD-chunked swizzle: hw block i -> logical (i&7)*64 + (i>>3).
    // XCD k gets logical 64k..64k+63 = planes 32k..32k+31, both halves.
    const int lb    = (blockIdx.x & 7) * 64 + (blockIdx.x >> 3);
    const int plane = lb >> 1;
    const int half  = lb & 1;
    const int rbase = half * OWN - HALO;        // window start row
    const int r0    = rbase + rg * RPT;         // this thread's first row
    const size_t pbase = (size_t)plane * PLANE;

    const float* __restrict__ xp = xin + pbase;
    const float* __restrict__ wb = wgt + pbase * 9;

    // ---- weights: k-outer independent stream, pack |.| fp16 UNNORMALIZED
    //      as loads arrive (rows 0-3 -> regs, row 4 -> LDS own-slot),
    //      fp32 sums on the side; normalize post-pass. ----
    __half2 wh[RPT - 1][9][2];          // 72 VGPRs
    float s[RPT][4];
    #pragma unroll
    for (int p = 0; p < RPT; ++p) { s[p][0] = s[p][1] = s[p][2] = s[p][3] = 0.f; }

    #pragma unroll
    for (int k = 0; k < 9; ++k) {
        float4 v[RPT];
        #pragma unroll
        for (int p = 0; p < RPT; ++p) {
            const int gr = r0 + p;
            v[p] = make_float4(1.f, 1.f, 1.f, 1.f);      // dummy for pad rows
            if ((unsigned)gr < (unsigned)H)
                v[p] = *reinterpret_cast<const float4*>(
                           wb + (size_t)k * PLANE + gr * W + j0);
        }
        #pragma unroll
        for (int p = 0; p < RPT; ++p) {
            const float a0 = fabsf(v[p].x), a1 = fabsf(v[p].y);
            const float a2 = fabsf(v[p].z), a3 = fabsf(v[p].w);
            s[p][0] += a0; s[p][1] += a1; s[p][2] += a2; s[p][3] += a3;
            const __half2 h0 = __halves2half2(__float2half_rn(a0), __float2half_rn(a1));
            const __half2 h1 = __halves2half2(__float2half_rn(a2), __float2half_rn(a3));
            if (p < RPT - 1) {
                wh[p][k][0] = h0;
                wh[p][k][1] = h1;
            } else {
                whL[k][tid] = make_uint2(__builtin_bit_cast(unsigned int, h0),
                                         __builtin_bit_cast(unsigned int, h1));
            }
        }
    }
    // normalize post-pass: rows 0-3 register-only
    #pragma unroll
    for (int p = 0; p < RPT - 1; ++p) {
        const float i0 = 1.f / s[p][0], i1 = 1.f / s[p][1];
        const float i2 = 1.f / s[p][2], i3 = 1.f / s[p][3];
        #pragma unroll
        for (int k = 0; k < 9; ++k) {
            wh[p][k][0] = __halves2half2(
                __float2half_rn(__low2float (wh[p][k][0]) * i0),
                __float2half_rn(__high2float(wh[p][k][0]) * i1));
            wh[p][k][1] = __halves2half2(
                __float2half_rn(__low2float (wh[p][k][1]) * i2),
                __float2half_rn(__high2float(wh[p][k][1]) * i3));
        }
    }
    // row 4: LDS own-slot read-modify-write (same thread, no barrier needed)
    {
        const float i0 = 1.f / s[RPT - 1][0], i1 = 1.f / s[RPT - 1][1];
        const float i2 = 1.f / s[RPT - 1][2], i3 = 1.f / s[RPT - 1][3];
        #pragma unroll
        for (int k = 0; k < 9; ++k) {
            const uint2 lv = whL[k][tid];
            const __half2 h0 = __builtin_bit_cast(__half2, lv.x);
            const __half2 h1 = __builtin_bit_cast(__half2, lv.y);
            const __half2 n0 = __halves2half2(
                __float2half_rn(__low2float (h0) * i0),
                __float2half_rn(__high2float(h0) * i1));
            const __half2 n1 = __halves2half2(
                __float2half_rn(__low2float (h1) * i2),
                __float2half_rn(__high2float(h1) * i3));
            whL[k][tid] = make_uint2(__builtin_bit_cast(unsigned int, n0),
                                     __builtin_bit_cast(unsigned int, n1));
        }
    }

    // ---- x window into registers (pad rows -> 0) ----
    float4 xr[RPT];
    #pragma unroll
    for (int p = 0; p < RPT; ++p) {
        const int gr = r0 + p;
        xr[p] = make_float4(0.f, 0.f, 0.f, 0.f);
        if ((unsigned)gr < (unsigned)H)
            xr[p] = *reinterpret_cast<const float4*>(xp + gr * W + j0);
    }

    // ---- 8 fused steps, zero global traffic, two barriers/step ----
    #pragma unroll 1
    for (int st = 0; st < NSTEP; ++st) {
        *reinterpret_cast<float4*>(&ldsT[rg][j0]) = xr[0];
        *reinterpret_cast<float4*>(&ldsB[rg][j0]) = xr[RPT - 1];
        __syncthreads();
        float4 up = make_float4(0.f, 0.f, 0.f, 0.f);   // row r0-1
        float4 dn = make_float4(0.f, 0.f, 0.f, 0.f);   // row r0+5
        if (rg > 0)       up = *reinterpret_cast<const float4*>(&ldsB[rg - 1][j0]);
        if (rg < NRG - 1) dn = *reinterpret_cast<const float4*>(&ldsT[rg + 1][j0]);
        __syncthreads();   // reads done before next step's writes

        float win[3][6];
        MKWIN(win[0], up);       // input row r0-1
        MKWIN(win[1], xr[0]);    // input row r0
        #pragma unroll
        for (int p = 0; p < RPT; ++p) {
            if (p < RPT - 1) { MKWIN(win[(p + 2) % 3], xr[p + 1]); }
            else             { MKWIN(win[(p + 2) % 3], dn); }
            float a0 = 0.f, a1 = 0.f, a2 = 0.f, a3 = 0.f;
            #pragma unroll
            for (int di = 0; di < 3; ++di) {
                #pragma unroll
                for (int dj = 0; dj < 3; ++dj) {
                    const int k = di * 3 + dj;
                    __half2 w0, w1;
                    if (p < RPT - 1) { w0 = wh[p][k][0]; w1 = wh[p][k][1]; }
                    else {
                        const uint2 lv = whL[k][tid];
                        w0 = __builtin_bit_cast(__half2, lv.x);
                        w1 = __builtin_bit_cast(__half2, lv.y);
                    }
                    a0 = fmaf(__low2float (w0), win[(p + di) % 3][dj + 0], a0);
                    a1 = fmaf(__high2float(w0), win[(p + di) % 3][dj + 1], a1);
                    a2 = fmaf(__low2float (w1), win[(p + di) % 3][dj + 2], a2);
                    a3 = fmaf(__high2float(w1), win[(p + di) % 3][dj + 3], a3);
                }
            }
            xr[p] = make_float4(a0, a1, a2, a3);
        }
        // re-impose zero padding (keeps pad rows 0 every step)
        #pragma unroll
        for (int p = 0; p < RPT; ++p) {
            const int gr = r0 + p;
            if ((unsigned)gr >= (unsigned)H)
                xr[p] = make_float4(0.f, 0.f, 0.f, 0.f);
        }
    }

    // ---- store owned rows only (coalesced float4) ----
    float* __restrict__ op = out + pbase;
    #pragma unroll
    for (int p = 0; p < RPT; ++p) {
        const int gr = r0 + p;
        const int lr = gr - half * OWN;
        if ((unsigned)lr < (unsigned)OWN)
            *reinterpret_cast<float4*>(op + gr * W + j0) = xr[p];
    }
}

extern "C" void kernel_launch(void* const* d_in, const int* in_sizes, int n_in,
                              void* d_out, int out_size, void* d_ws, size_t ws_size,
                              hipStream_t stream)
{
    const float* x = (const float*)d_in[0];
    const float* w = (const float*)d_in[1];
    float* out = (float*)d_out;
    (void)d_ws; (void)ws_size; (void)in_sizes; (void)n_in; (void)out_size;

    // 512 blocks = 2 per plane (4n x 64c), 512 threads
    diff_fused<<<dim3(2 * 4 * 64), dim3(512), 0, stream>>>(x, w, out);
}